// Round 1
// baseline (261.695 us; speedup 1.0000x reference)
//
#include <hip/hip_runtime.h>
#include <stdint.h>

typedef float v4f __attribute__((ext_vector_type(4)));
typedef short v8s __attribute__((ext_vector_type(8)));
typedef uint32_t u32;

#define DEVI static __device__ __forceinline__

// fp32 -> bf16 (RNE), raw bits
DEVI unsigned short f2bf(float f) {
    u32 u = __builtin_bit_cast(u32, f);
    u = (u + 0x7fffu + ((u >> 16) & 1u)) >> 16;
    return (unsigned short)u;
}
DEVI float bf2f(unsigned short h) {
    u32 u = ((u32)h) << 16;
    return __builtin_bit_cast(float, u);
}

// async global->LDS, 16B per lane. LDS dest must be linear: base + lane*16.
DEVI void async16(const unsigned short* g, unsigned short* l) {
    __builtin_amdgcn_global_load_lds(
        (const __attribute__((address_space(1))) u32*)g,
        (__attribute__((address_space(3))) u32*)l, 16, 0, 0);
}

// ---------------------------------------------------------------------------
// prep: fp32 [R][512] -> bf16, row sum-of-squares, optional row sum.
// one wave per row; grid = R/4 blocks of 256.
__launch_bounds__(256, 2)
__global__ void prep_rows(const float* __restrict__ X, unsigned short* __restrict__ Xb,
                          float* __restrict__ Sq, float* __restrict__ Rs, int hasRs)
{
    const int w = threadIdx.x >> 6, lane = threadIdx.x & 63;
    const int r = blockIdx.x * 4 + w;
    const float* xr = X + (size_t)r * 512 + lane * 8;
    float4 a = *(const float4*)xr;
    float4 c = *(const float4*)(xr + 4);
    float s = a.x*a.x + a.y*a.y + a.z*a.z + a.w*a.w
            + c.x*c.x + c.y*c.y + c.z*c.z + c.w*c.w;
    float sm = a.x + a.y + a.z + a.w + c.x + c.y + c.z + c.w;
    uint4 pkv;
    unsigned short* e = (unsigned short*)&pkv;
    e[0] = f2bf(a.x); e[1] = f2bf(a.y); e[2] = f2bf(a.z); e[3] = f2bf(a.w);
    e[4] = f2bf(c.x); e[5] = f2bf(c.y); e[6] = f2bf(c.z); e[7] = f2bf(c.w);
    *(uint4*)(Xb + (size_t)r * 512 + lane * 8) = pkv;
#pragma unroll
    for (int d = 32; d > 0; d >>= 1) {
        s  += __shfl_xor(s, d);
        sm += __shfl_xor(sm, d);
    }
    if (lane == 0) { Sq[r] = s; if (hasRs) Rs[r] = sm; }
}

// ---------------------------------------------------------------------------
// k'_sq over bf16 k' [32*2048][64]; 8 lanes per row.
__launch_bounds__(256, 2)
__global__ void ksq_kernel(const unsigned short* __restrict__ Kp, float* __restrict__ Ksq)
{
    const int t = threadIdx.x;
    const int r = blockIdx.x * 32 + (t >> 3);
    uint4 pk = *(const uint4*)(Kp + (size_t)r * 64 + (t & 7) * 8);
    const unsigned short* e = (const unsigned short*)&pk;
    float s = 0.f;
#pragma unroll
    for (int u = 0; u < 8; ++u) { float f = bf2f(e[u]); s += f * f; }
#pragma unroll
    for (int d = 1; d < 8; d <<= 1) s += __shfl_xor(s, d);
    if ((t & 7) == 0) Ksq[r] = s;
}

// ---------------------------------------------------------------------------
// out_sq = sum_d (out'[r][d] + 32)^2 over bf16 out' [8192][512]; wave per row.
__launch_bounds__(256, 2)
__global__ void outsq_kernel(const unsigned short* __restrict__ Op, float* __restrict__ Osq)
{
    const int w = threadIdx.x >> 6, lane = threadIdx.x & 63;
    const int r = blockIdx.x * 4 + w;
    uint4 pk = *(const uint4*)(Op + (size_t)r * 512 + lane * 8);
    const unsigned short* e = (const unsigned short*)&pk;
    float s = 0.f;
#pragma unroll
    for (int u = 0; u < 8; ++u) { float f = bf2f(e[u]) + 32.f; s += f * f; }
#pragma unroll
    for (int d = 32; d > 0; d >>= 1) s += __shfl_xor(s, d);
    if (lane == 0) Osq[r] = s;
}

// ---------------------------------------------------------------------------
// cdist GEMM: C[r][c] from dot(A_r, B_c), A [M][K] bf16, B [Ncols][K] bf16 (B^T form).
// 128x128 tile, BK=64, 4 waves, 16x16x32 bf16 MFMA, XOR-8 LDS swizzle,
// global_load_lds width-16 staging (swizzle applied on the global side).
// MODE 0: val = sqrt(max(Asq+Bsq-2dot,0)) - 32, scatter to q'/k'/v' (q pre-scaled).
// MODE 1: val = sqrt(max(Asq+Bsq-2(dot+32*Brs[c]),0)) -> fp32 OUT.
template<int MODE>
__launch_bounds__(256, 2)
__global__ void gemm_cdist(const unsigned short* __restrict__ A,
                           const unsigned short* __restrict__ B,
                           const float* __restrict__ Asq,
                           const float* __restrict__ Bsq,
                           const float* __restrict__ Brs,
                           unsigned short* __restrict__ QKV,
                           float* __restrict__ OUT,
                           int Ncols, int Kdim)
{
    __shared__ unsigned short lA[128 * 64];
    __shared__ unsigned short lB[128 * 64];
    const int t = threadIdx.x;
    const int lane = t & 63, w = t >> 6;
    const int low = lane & 15, quad = lane >> 4;
    const int wm = w & 1, wn = w >> 1;
    const int tM = blockIdx.x * 128, tN = blockIdx.y * 128;

    v4f acc[4][4];
#pragma unroll
    for (int a = 0; a < 4; ++a)
#pragma unroll
        for (int b = 0; b < 4; ++b) acc[a][b] = (v4f){0.f, 0.f, 0.f, 0.f};

    for (int kt = 0; kt < Kdim; kt += 64) {
        __syncthreads();
#pragma unroll
        for (int is = 0; is < 4; ++is) {
            int slot = is * 256 + t;          // 16B units; lds off = slot*16 (linear)
            int r = slot >> 3, bp = slot & 7;
            int bs = bp ^ (r & 7);            // global 16B block that belongs at bp
            async16(A + (size_t)(tM + r) * Kdim + kt + bs * 8, lA + slot * 8);
            async16(B + (size_t)(tN + r) * Kdim + kt + bs * 8, lB + slot * 8);
        }
        __syncthreads();

        v8s bfr[4][2];
#pragma unroll
        for (int ns = 0; ns < 4; ++ns) {
            int row = wn * 64 + ns * 16 + low;
#pragma unroll
            for (int kc = 0; kc < 2; ++kc)
                bfr[ns][kc] = *(const v8s*)(lB + (row * 8 + ((kc * 4 + quad) ^ (row & 7))) * 8);
        }
#pragma unroll
        for (int ms = 0; ms < 4; ++ms) {
            int row = wm * 64 + ms * 16 + low;
            v8s af0 = *(const v8s*)(lA + (row * 8 + ((0 + quad) ^ (row & 7))) * 8);
            v8s af1 = *(const v8s*)(lA + (row * 8 + ((4 + quad) ^ (row & 7))) * 8);
#pragma unroll
            for (int ns = 0; ns < 4; ++ns) {
                acc[ms][ns] = __builtin_amdgcn_mfma_f32_16x16x32_bf16(af0, bfr[ns][0], acc[ms][ns], 0, 0, 0);
                acc[ms][ns] = __builtin_amdgcn_mfma_f32_16x16x32_bf16(af1, bfr[ns][1], acc[ms][ns], 0, 0, 0);
            }
        }
    }

#pragma unroll
    for (int ms = 0; ms < 4; ++ms) {
#pragma unroll
        for (int ns = 0; ns < 4; ++ns) {
#pragma unroll
            for (int reg = 0; reg < 4; ++reg) {
                int row = tM + wm * 64 + ms * 16 + quad * 4 + reg;  // C row
                int col = tN + wn * 64 + ns * 16 + low;             // C col
                float dot = acc[ms][ns][reg];
                if (MODE == 0) {
                    float val = sqrtf(fmaxf(Asq[row] + Bsq[col] - 2.f * dot, 0.f)) - 32.f;
                    int tt = col >> 9, h = (col >> 6) & 7, d = col & 63;
                    int b = row >> 11, i = row & 2047;
                    if (tt == 0) val *= 0.36067376022224085f;  // 2*scale*log2e folded into q'
                    QKV[((size_t)(tt * 32 + b * 8 + h) * 2048 + i) * 64 + d] = f2bf(val);
                } else {
                    float val = sqrtf(fmaxf(Asq[row] + Bsq[col]
                                            - 2.f * (dot + 32.f * Brs[col]), 0.f));
                    OUT[(size_t)row * Ncols + col] = val;
                }
            }
        }
    }
}

// ---------------------------------------------------------------------------
// Flash attention over centered bf16 q''/k'/v'. Scores (exp2 domain):
//   s2 = q''.k' - 0.18033688*k'_sq   (q'_sq row-constant, dropped; q'' pre-scaled)
// Block: 64 Q-rows (4 waves x 16), K/V tiles of 64. Online softmax.
// Output: out' = attn @ v' (centered by 32), bf16 [8192][512].
__launch_bounds__(256, 2)
__global__ void flash_attn(const unsigned short* __restrict__ Q,
                           const unsigned short* __restrict__ K,
                           const unsigned short* __restrict__ V,
                           const float* __restrict__ Ksq,
                           unsigned short* __restrict__ O)
{
    __shared__ unsigned short lK[64 * 64];      // row-major [j][d], XOR-8 block swizzle
    __shared__ unsigned short lV[64 * 64];      // transposed [d][j], XOR-8 block swizzle
    __shared__ unsigned short lP[4][16 * 64];   // per-wave P, [i][j], XOR-8 swizzle
    const int t = threadIdx.x;
    const int lane = t & 63, w = t >> 6;
    const int low = lane & 15, quad = lane >> 4;
    const int qt = blockIdx.x, bh = blockIdx.y;
    const size_t base = (size_t)bh * (2048 * 64);

    v8s qf0, qf1;
    {
        const unsigned short* qr = Q + base + (size_t)(qt * 64 + w * 16 + low) * 64 + quad * 8;
        qf0 = *(const v8s*)(qr);
        qf1 = *(const v8s*)(qr + 32);
    }

    float m_i[4], l_i[4];
    v4f o[4];
#pragma unroll
    for (int r = 0; r < 4; ++r) { m_i[r] = -1e30f; l_i[r] = 0.f; o[r] = (v4f){0.f,0.f,0.f,0.f}; }

    const float* ksqb = Ksq + bh * 2048;

    for (int jt = 0; jt < 2048; jt += 64) {
        __syncthreads();
        // K tile: async global->LDS, swizzle on global side
#pragma unroll
        for (int is = 0; is < 2; ++is) {
            int slot = is * 256 + t;
            int r = slot >> 3, bp = slot & 7, bs = bp ^ (r & 7);
            async16(K + base + (size_t)(jt + r) * 64 + bs * 8, lK + slot * 8);
        }
        // V tile: manual transposed store [d][j]
#pragma unroll
        for (int ps = 0; ps < 2; ++ps) {
            int j = ps * 32 + (t >> 3);
            int d0 = (t & 7) * 8;
            uint4 pk = *(const uint4*)(V + base + (size_t)(jt + j) * 64 + d0);
            const unsigned short* e = (const unsigned short*)&pk;
            int jb = j >> 3, j7 = j & 7;
#pragma unroll
            for (int u = 0; u < 8; ++u) {
                int d = d0 + u;
                lV[d * 64 + (((jb ^ (d >> 3)) << 3) | j7)] = e[u];
            }
        }
        __syncthreads();

        // ---- S phase: 4 j-subtiles of 16 ----
        float p[4][4];
        float mcur[4];
#pragma unroll
        for (int r = 0; r < 4; ++r) mcur[r] = -1e30f;
#pragma unroll
        for (int js = 0; js < 4; ++js) {
            int row = js * 16 + low;
            v8s kf0 = *(const v8s*)(lK + (row * 8 + ((0 + quad) ^ (row & 7))) * 8);
            v8s kf1 = *(const v8s*)(lK + (row * 8 + ((4 + quad) ^ (row & 7))) * 8);
            v4f dotf = (v4f){0.f,0.f,0.f,0.f};
            dotf = __builtin_amdgcn_mfma_f32_16x16x32_bf16(qf0, kf0, dotf, 0, 0, 0);
            dotf = __builtin_amdgcn_mfma_f32_16x16x32_bf16(qf1, kf1, dotf, 0, 0, 0);
            float kq = ksqb[jt + row] * 0.18033688011112042f;  // scale*log2e
#pragma unroll
            for (int r = 0; r < 4; ++r) {
                float s = dotf[r] - kq;
                p[js][r] = s;
                mcur[r] = fmaxf(mcur[r], s);
            }
        }
        // row max across the 16 lanes holding one row
#pragma unroll
        for (int r = 0; r < 4; ++r) {
#pragma unroll
            for (int d = 1; d < 16; d <<= 1) mcur[r] = fmaxf(mcur[r], __shfl_xor(mcur[r], d));
        }
        float alpha[4], rsum[4];
#pragma unroll
        for (int r = 0; r < 4; ++r) {
            float mn = fmaxf(m_i[r], mcur[r]);
            alpha[r] = exp2f(m_i[r] - mn);
            m_i[r] = mn;
            rsum[r] = 0.f;
        }
        // p = exp2(s - m), write bf16 P to per-wave LDS
#pragma unroll
        for (int js = 0; js < 4; ++js) {
            int j = js * 16 + low;
            int jb = j >> 3, j7 = j & 7;
#pragma unroll
            for (int r = 0; r < 4; ++r) {
                float pv = exp2f(p[js][r] - m_i[r]);
                rsum[r] += pv;
                int prow = quad * 4 + r;
                lP[w][prow * 64 + (((jb ^ (prow & 7)) << 3) | j7)] = f2bf(pv);
            }
        }
#pragma unroll
        for (int r = 0; r < 4; ++r) {
#pragma unroll
            for (int d = 1; d < 16; d <<= 1) rsum[r] += __shfl_xor(rsum[r], d);
            l_i[r] = l_i[r] * alpha[r] + rsum[r];
        }
#pragma unroll
        for (int ds = 0; ds < 4; ++ds)
#pragma unroll
            for (int r = 0; r < 4; ++r) o[ds][r] *= alpha[r];

        // drain this wave's P writes before reading them as A-frags
        __asm__ volatile("s_waitcnt lgkmcnt(0)" ::: "memory");

        v8s pf0 = *(const v8s*)(lP[w] + (low * 8 + ((0 + quad) ^ (low & 7))) * 8);
        v8s pf1 = *(const v8s*)(lP[w] + (low * 8 + ((4 + quad) ^ (low & 7))) * 8);
#pragma unroll
        for (int ds = 0; ds < 4; ++ds) {
            int d = ds * 16 + low;
            int sw = d >> 3;
            v8s vf0 = *(const v8s*)(lV + d * 64 + (((0 + quad) ^ sw) << 3));
            v8s vf1 = *(const v8s*)(lV + d * 64 + (((4 + quad) ^ sw) << 3));
            o[ds] = __builtin_amdgcn_mfma_f32_16x16x32_bf16(pf0, vf0, o[ds], 0, 0, 0);
            o[ds] = __builtin_amdgcn_mfma_f32_16x16x32_bf16(pf1, vf1, o[ds], 0, 0, 0);
        }
    }

    const int b = bh >> 3, h = bh & 7;
#pragma unroll
    for (int r = 0; r < 4; ++r) l_i[r] = 1.f / l_i[r];
#pragma unroll
    for (int ds = 0; ds < 4; ++ds) {
#pragma unroll
        for (int r = 0; r < 4; ++r) {
            int i = qt * 64 + w * 16 + quad * 4 + r;
            int col = h * 64 + ds * 16 + low;
            O[(size_t)(b * 2048 + i) * 512 + col] = f2bf(o[ds][r] * l_i[r]);
        }
    }
}

// ---------------------------------------------------------------------------
extern "C" void kernel_launch(void* const* d_in, const int* in_sizes, int n_in,
                              void* d_out, int out_size, void* d_ws, size_t ws_size,
                              hipStream_t stream)
{
    const float* x    = (const float*)d_in[0];   // [4,2048,512]
    const float* wqkv = (const float*)d_in[1];   // [1536,512]
    const float* wout = (const float*)d_in[2];   // [512,512]
    float* out = (float*)d_out;                  // [4,2048,512] fp32

    char* ws = (char*)d_ws;
    size_t off = 0;
    auto alloc = [&](size_t bytes) -> void* {
        void* p = ws + off;
        off += (bytes + 255) & ~(size_t)255;
        return p;
    };
    unsigned short* xb   = (unsigned short*)alloc(8192ull * 512 * 2);
    unsigned short* wqb  = (unsigned short*)alloc(1536ull * 512 * 2);
    unsigned short* wob  = (unsigned short*)alloc(512ull * 512 * 2);
    unsigned short* qkv  = (unsigned short*)alloc(3ull * 32 * 2048 * 64 * 2);  // q'',k',v'
    unsigned short* outp = (unsigned short*)alloc(8192ull * 512 * 2);
    float* xsq  = (float*)alloc(8192 * 4);
    float* wqsq = (float*)alloc(1536 * 4);
    float* wosq = (float*)alloc(512 * 4);
    float* wors = (float*)alloc(512 * 4);
    float* ksq  = (float*)alloc(65536ull * 4);
    float* osq  = (float*)alloc(8192 * 4);

    const size_t HSZ = 32ull * 2048 * 64;  // per q/k/v region, elements

    prep_rows<<<2048, 256, 0, stream>>>(x, xb, xsq, nullptr, 0);
    prep_rows<<<384, 256, 0, stream>>>(wqkv, wqb, wqsq, nullptr, 0);
    prep_rows<<<128, 256, 0, stream>>>(wout, wob, wosq, wors, 1);

    gemm_cdist<0><<<dim3(64, 12), 256, 0, stream>>>(xb, wqb, xsq, wqsq, nullptr,
                                                    qkv, nullptr, 1536, 512);
    ksq_kernel<<<2048, 256, 0, stream>>>(qkv + HSZ, ksq);
    flash_attn<<<dim3(32, 32), 256, 0, stream>>>(qkv, qkv + HSZ, qkv + 2 * HSZ, ksq, outp);
    outsq_kernel<<<2048, 256, 0, stream>>>(outp, osq);
    gemm_cdist<1><<<dim3(64, 4), 256, 0, stream>>>(outp, wob, osq, wosq, wors,
                                                   nullptr, out, 512, 512);
}

// Round 2
// 210.426 us; speedup vs baseline: 1.2436x; 1.2436x over previous
//
#include <hip/hip_runtime.h>
#include <stdint.h>

typedef float v4f __attribute__((ext_vector_type(4)));
typedef short v8s __attribute__((ext_vector_type(8)));
typedef uint32_t u32;

#define DEVI static __device__ __forceinline__

// fp32 -> bf16 (RNE), raw bits
DEVI unsigned short f2bf(float f) {
    u32 u = __builtin_bit_cast(u32, f);
    u = (u + 0x7fffu + ((u >> 16) & 1u)) >> 16;
    return (unsigned short)u;
}
DEVI float bf2f(unsigned short h) {
    u32 u = ((u32)h) << 16;
    return __builtin_bit_cast(float, u);
}

// async global->LDS, 16B per lane. HW dest = wave-uniform base + lane*16,
// which matches all call sites below (lds ptr is linear in lane).
template <typename T>
DEVI void async16(const T* g, T* l) {
    __builtin_amdgcn_global_load_lds(
        (const __attribute__((address_space(1))) u32*)g,
        (__attribute__((address_space(3))) u32*)l, 16, 0, 0);
}

DEVI v4f bmfma(v8s a, v8s b, v4f c) {
    return __builtin_amdgcn_mfma_f32_16x16x32_bf16(a, b, c, 0, 0, 0);
}

static const size_t HSZ = 32ull * 2048 * 64;  // per q/k/v region, elements

// ---------------------------------------------------------------------------
// prep: fp32 [R][512] -> bf16, row sum-of-squares, optional row sum.
__launch_bounds__(256, 2)
__global__ void prep_rows(const float* __restrict__ X, unsigned short* __restrict__ Xb,
                          float* __restrict__ Sq, float* __restrict__ Rs, int hasRs)
{
    const int w = threadIdx.x >> 6, lane = threadIdx.x & 63;
    const int r = blockIdx.x * 4 + w;
    const float* xr = X + (size_t)r * 512 + lane * 8;
    float4 a = *(const float4*)xr;
    float4 c = *(const float4*)(xr + 4);
    float s = a.x*a.x + a.y*a.y + a.z*a.z + a.w*a.w
            + c.x*c.x + c.y*c.y + c.z*c.z + c.w*c.w;
    float sm = a.x + a.y + a.z + a.w + c.x + c.y + c.z + c.w;
    uint4 pkv;
    unsigned short* e = (unsigned short*)&pkv;
    e[0] = f2bf(a.x); e[1] = f2bf(a.y); e[2] = f2bf(a.z); e[3] = f2bf(a.w);
    e[4] = f2bf(c.x); e[5] = f2bf(c.y); e[6] = f2bf(c.z); e[7] = f2bf(c.w);
    *(uint4*)(Xb + (size_t)r * 512 + lane * 8) = pkv;
#pragma unroll
    for (int d = 32; d > 0; d >>= 1) {
        s  += __shfl_xor(s, d);
        sm += __shfl_xor(sm, d);
    }
    if (lane == 0) { Sq[r] = s; if (hasRs) Rs[r] = sm; }
}

// ---------------------------------------------------------------------------
// out_sq = sum_d (out'[r][d] + 32)^2 over bf16 out' [8192][512]; wave per row.
__launch_bounds__(256, 2)
__global__ void outsq_kernel(const unsigned short* __restrict__ Op, float* __restrict__ Osq)
{
    const int w = threadIdx.x >> 6, lane = threadIdx.x & 63;
    const int r = blockIdx.x * 4 + w;
    uint4 pk = *(const uint4*)(Op + (size_t)r * 512 + lane * 8);
    const unsigned short* e = (const unsigned short*)&pk;
    float s = 0.f;
#pragma unroll
    for (int u = 0; u < 8; ++u) { float f = bf2f(e[u]) + 32.f; s += f * f; }
#pragma unroll
    for (int d = 32; d > 0; d >>= 1) s += __shfl_xor(s, d);
    if (lane == 0) Osq[r] = s;
}

// ---------------------------------------------------------------------------
// cdist GEMM. 128x128 tile, BK=64, 4 waves, 16x16x32 bf16 MFMA, XOR-8 swizzle,
// global_load_lds width-16 staging.
// MODE 0: val = sqrt(max(Asq+Bsq-2dot,0)) - 32.
//   tt=0 (q): *CQ -> q'' region [bh][i][d]
//   tt=1 (k): -> k' region [bh][j][d]; fused ksqc[bh][j] = sum_d k'^2 * CK
//   tt=2 (v): -> v' region TRANSPOSED [bh][d][j]
// MODE 1: val = sqrt(max(Asq+Bsq-2(dot+32*Brs[c]),0)) -> fp32 OUT.
template<int MODE>
__launch_bounds__(256, 2)
__global__ void gemm_cdist(const unsigned short* __restrict__ A,
                           const unsigned short* __restrict__ B,
                           const float* __restrict__ Asq,
                           const float* __restrict__ Bsq,
                           const float* __restrict__ Brs,
                           unsigned short* __restrict__ QKV,
                           float* __restrict__ OUT,
                           float* __restrict__ Ksqc,
                           int Ncols, int Kdim)
{
    __shared__ unsigned short lA[128 * 64];
    __shared__ unsigned short lB[128 * 64];
    const int t = threadIdx.x;
    const int lane = t & 63, w = t >> 6;
    const int low = lane & 15, quad = lane >> 4;
    const int wm = w & 1, wn = w >> 1;
    const int tM = blockIdx.x * 128, tN = blockIdx.y * 128;

    v4f acc[4][4];
#pragma unroll
    for (int a = 0; a < 4; ++a)
#pragma unroll
        for (int b = 0; b < 4; ++b) acc[a][b] = (v4f){0.f, 0.f, 0.f, 0.f};

    for (int kt = 0; kt < Kdim; kt += 64) {
        __syncthreads();
#pragma unroll
        for (int is = 0; is < 4; ++is) {
            int slot = is * 256 + t;
            int r = slot >> 3, bp = slot & 7;
            int bs = bp ^ (r & 7);
            async16(A + (size_t)(tM + r) * Kdim + kt + bs * 8, lA + slot * 8);
            async16(B + (size_t)(tN + r) * Kdim + kt + bs * 8, lB + slot * 8);
        }
        __syncthreads();

        v8s bfr[4][2];
#pragma unroll
        for (int ns = 0; ns < 4; ++ns) {
            int row = wn * 64 + ns * 16 + low;
#pragma unroll
            for (int kc = 0; kc < 2; ++kc)
                bfr[ns][kc] = *(const v8s*)(lB + (row * 8 + ((kc * 4 + quad) ^ (row & 7))) * 8);
        }
#pragma unroll
        for (int ms = 0; ms < 4; ++ms) {
            int row = wm * 64 + ms * 16 + low;
            v8s af0 = *(const v8s*)(lA + (row * 8 + ((0 + quad) ^ (row & 7))) * 8);
            v8s af1 = *(const v8s*)(lA + (row * 8 + ((4 + quad) ^ (row & 7))) * 8);
#pragma unroll
            for (int ns = 0; ns < 4; ++ns) {
                acc[ms][ns] = bmfma(af0, bfr[ns][0], acc[ms][ns]);
                acc[ms][ns] = bmfma(af1, bfr[ns][1], acc[ms][ns]);
            }
        }
    }

    const int tt = tN >> 9;  // wave-uniform region id for MODE 0
#pragma unroll
    for (int ms = 0; ms < 4; ++ms) {
#pragma unroll
        for (int reg = 0; reg < 4; ++reg) {
            const int row = tM + wm * 64 + ms * 16 + quad * 4 + reg;
            const int b = row >> 11, i = row & 2047;
            float kacc = 0.f;
#pragma unroll
            for (int ns = 0; ns < 4; ++ns) {
                const int col = tN + wn * 64 + ns * 16 + low;
                float dot = acc[ms][ns][reg];
                if (MODE == 0) {
                    float val = sqrtf(fmaxf(Asq[row] + Bsq[col] - 2.f * dot, 0.f)) - 32.f;
                    int h = (col >> 6) & 7, d = col & 63, bh = b * 8 + h;
                    if (tt == 0) {
                        QKV[((size_t)bh * 2048 + i) * 64 + d] =
                            f2bf(val * 0.36067376022224085f);  // 2*scale*log2e
                    } else if (tt == 1) {
                        QKV[HSZ + ((size_t)bh * 2048 + i) * 64 + d] = f2bf(val);
                        kacc += val * val;
                    } else {
                        QKV[2 * HSZ + ((size_t)(bh * 64 + d)) * 2048 + i] = f2bf(val);
                    }
                } else {
                    float val = sqrtf(fmaxf(Asq[row] + Bsq[col]
                                            - 2.f * (dot + 32.f * Brs[col]), 0.f));
                    OUT[(size_t)row * Ncols + col] = val;
                }
            }
            if (MODE == 0 && tt == 1) {
#pragma unroll
                for (int d = 1; d < 16; d <<= 1) kacc += __shfl_xor(kacc, d);
                if (low == 0) {
                    int h = ((tN + wn * 64) >> 6) & 7;
                    Ksqc[(size_t)(b * 8 + h) * 2048 + i] = kacc * 0.18033688011112042f;
                }
            }
        }
    }
}

// ---------------------------------------------------------------------------
// Flash attention, static-bound softmax (no online max).
// Block: 2 waves x 32 Q-rows = 64 rows. K/V tiles of 64 j.
// exp2-domain score = q''.k' - ksqc[j] - mq[i], all terms pre-scaled.
__launch_bounds__(128, 2)
__global__ void flash_attn(const unsigned short* __restrict__ Q,
                           const unsigned short* __restrict__ K,
                           const unsigned short* __restrict__ VT,
                           const float* __restrict__ Ksqc,
                           unsigned short* __restrict__ O)
{
    __shared__ unsigned short lK[64 * 64];        // [j][d], XOR-8 swizzle
    __shared__ unsigned short lV[64 * 64];        // [d][j], XOR-8 swizzle
    __shared__ float lKq[64];
    __shared__ __align__(16) u32 lP2[2][16 * 68]; // per wave: 16 row-pairs x 64 j (+4 pad)

    const int t = threadIdx.x, lane = t & 63, w = t >> 6;
    const int low = lane & 15, quad = lane >> 4;
    const int qt = blockIdx.x, bh = blockIdx.y;
    const size_t base = (size_t)bh * (2048 * 64);
    const int row0 = qt * 64 + w * 32;

    // Q fragments: rows row0 + g*16 + low
    v8s qf[2][2];
#pragma unroll
    for (int g = 0; g < 2; ++g)
#pragma unroll
        for (int kc = 0; kc < 2; ++kc)
            qf[g][kc] = *(const v8s*)(Q + base + (size_t)(row0 + g * 16 + low) * 64
                                      + kc * 32 + quad * 8);

    // static per-row softmax shift: mq = q''_sq / (4*scale*log2e) = q'_sq*scale*log2e
    v4f negmq[2];
#pragma unroll
    for (int g = 0; g < 2; ++g) {
        float s = 0.f;
#pragma unroll
        for (int kc = 0; kc < 2; ++kc) {
            const unsigned short* qe = (const unsigned short*)&qf[g][kc];
#pragma unroll
            for (int u = 0; u < 8; ++u) { float f = bf2f(qe[u]); s += f * f; }
        }
        s += __shfl_xor(s, 16);
        s += __shfl_xor(s, 32);
        float m = s * 1.3862943611198906f;
#pragma unroll
        for (int r = 0; r < 4; ++r) negmq[g][r] = -__shfl(m, quad * 4 + r);
    }

    v4f o[2][4], lsum[2];
#pragma unroll
    for (int g = 0; g < 2; ++g) {
        lsum[g] = (v4f){0.f, 0.f, 0.f, 0.f};
#pragma unroll
        for (int ds = 0; ds < 4; ++ds) o[g][ds] = (v4f){0.f, 0.f, 0.f, 0.f};
    }

    for (int jt = 0; jt < 2048; jt += 64) {
        __syncthreads();
#pragma unroll
        for (int is = 0; is < 4; ++is) {
            int slot = is * 128 + t;
            int r = slot >> 3, bp = slot & 7, bs = bp ^ (r & 7);
            async16(K + base + (size_t)(jt + r) * 64 + bs * 8, lK + slot * 8);
        }
#pragma unroll
        for (int is = 0; is < 4; ++is) {
            int slot = is * 128 + t;
            int r = slot >> 3, bp = slot & 7, bs = bp ^ (r & 7);
            async16(VT + (size_t)(bh * 64 + r) * 2048 + jt + bs * 8, lV + slot * 8);
        }
        if (t < 16) async16(Ksqc + (size_t)bh * 2048 + jt + t * 4, lKq + t * 4);
        __syncthreads();

        // ---- S phase ----
#pragma unroll
        for (int js = 0; js < 4; ++js) {
            const int krow = js * 16 + low;
            v8s kf0 = *(const v8s*)(lK + (krow * 8 + ((0 + quad) ^ (krow & 7))) * 8);
            v8s kf1 = *(const v8s*)(lK + (krow * 8 + ((4 + quad) ^ (krow & 7))) * 8);
            float kq = lKq[krow];
#pragma unroll
            for (int g = 0; g < 2; ++g) {
                v4f sa = negmq[g];
                sa = bmfma(qf[g][0], kf0, sa);
                sa = bmfma(qf[g][1], kf1, sa);
                float pv0 = exp2f(sa[0] - kq);
                float pv1 = exp2f(sa[1] - kq);
                float pv2 = exp2f(sa[2] - kq);
                float pv3 = exp2f(sa[3] - kq);
                lsum[g][0] += pv0; lsum[g][1] += pv1;
                lsum[g][2] += pv2; lsum[g][3] += pv3;
                // pack row-pairs (round-half-up bf16) -> u32
                u32 pk0 = __builtin_amdgcn_perm(__builtin_bit_cast(u32, pv1) + 0x8000u,
                                                __builtin_bit_cast(u32, pv0) + 0x8000u,
                                                0x07060302u);
                u32 pk1 = __builtin_amdgcn_perm(__builtin_bit_cast(u32, pv3) + 0x8000u,
                                                __builtin_bit_cast(u32, pv2) + 0x8000u,
                                                0x07060302u);
                lP2[w][(g * 8 + quad * 2 + 0) * 68 + krow] = pk0;
                lP2[w][(g * 8 + quad * 2 + 1) * 68 + krow] = pk1;
            }
        }

        // wave-local P2 write->read ordering
        __asm__ volatile("s_waitcnt lgkmcnt(0)" ::: "memory");

        // ---- unpack P fragments ----
        v8s pf[2][2];
#pragma unroll
        for (int g = 0; g < 2; ++g)
#pragma unroll
            for (int kc = 0; kc < 2; ++kc) {
                const u32* pb = &lP2[w][(g * 8 + (low >> 1)) * 68 + kc * 32 + quad * 8];
                uint4 q0 = *(const uint4*)pb;
                uint4 q1 = *(const uint4*)(pb + 4);
                u32 sel = (low & 1) ? 0x07060302u : 0x05040100u;
                uint4 dd;
                dd.x = __builtin_amdgcn_perm(q0.y, q0.x, sel);
                dd.y = __builtin_amdgcn_perm(q0.w, q0.z, sel);
                dd.z = __builtin_amdgcn_perm(q1.y, q1.x, sel);
                dd.w = __builtin_amdgcn_perm(q1.w, q1.z, sel);
                pf[g][kc] = __builtin_bit_cast(v8s, dd);
            }

        // ---- PV phase ----
#pragma unroll
        for (int ds = 0; ds < 4; ++ds) {
            const int dd2 = ds * 16 + low;
#pragma unroll
            for (int kc = 0; kc < 2; ++kc) {
                v8s vf = *(const v8s*)(lV + (dd2 * 8 + ((kc * 4 + quad) ^ (dd2 & 7))) * 8);
                o[0][ds] = bmfma(pf[0][kc], vf, o[0][ds]);
                o[1][ds] = bmfma(pf[1][kc], vf, o[1][ds]);
            }
        }
    }

    // epilogue: deferred l reduction + normalize + store
    const int b = bh >> 3, h = bh & 7;
#pragma unroll
    for (int g = 0; g < 2; ++g) {
#pragma unroll
        for (int d = 1; d < 16; d <<= 1) {
#pragma unroll
            for (int r = 0; r < 4; ++r) lsum[g][r] += __shfl_xor(lsum[g][r], d);
        }
        v4f inv;
#pragma unroll
        for (int r = 0; r < 4; ++r) inv[r] = 1.f / lsum[g][r];
#pragma unroll
        for (int ds = 0; ds < 4; ++ds)
#pragma unroll
            for (int r = 0; r < 4; ++r) {
                int i = row0 + g * 16 + quad * 4 + r;
                O[((size_t)(b * 2048 + i)) * 512 + h * 64 + ds * 16 + low] =
                    f2bf(o[g][ds][r] * inv[r]);
            }
    }
}

// ---------------------------------------------------------------------------
extern "C" void kernel_launch(void* const* d_in, const int* in_sizes, int n_in,
                              void* d_out, int out_size, void* d_ws, size_t ws_size,
                              hipStream_t stream)
{
    const float* x    = (const float*)d_in[0];   // [4,2048,512]
    const float* wqkv = (const float*)d_in[1];   // [1536,512]
    const float* wout = (const float*)d_in[2];   // [512,512]
    float* out = (float*)d_out;                  // [4,2048,512] fp32

    char* ws = (char*)d_ws;
    size_t off = 0;
    auto alloc = [&](size_t bytes) -> void* {
        void* p = ws + off;
        off += (bytes + 255) & ~(size_t)255;
        return p;
    };
    unsigned short* xb   = (unsigned short*)alloc(8192ull * 512 * 2);
    unsigned short* wqb  = (unsigned short*)alloc(1536ull * 512 * 2);
    unsigned short* wob  = (unsigned short*)alloc(512ull * 512 * 2);
    unsigned short* qkv  = (unsigned short*)alloc(3ull * HSZ * 2);  // q'', k', v'^T
    unsigned short* outp = (unsigned short*)alloc(8192ull * 512 * 2);
    float* xsq  = (float*)alloc(8192 * 4);
    float* wqsq = (float*)alloc(1536 * 4);
    float* wosq = (float*)alloc(512 * 4);
    float* wors = (float*)alloc(512 * 4);
    float* ksqc = (float*)alloc(65536ull * 4);
    float* osq  = (float*)alloc(8192 * 4);

    prep_rows<<<2048, 256, 0, stream>>>(x, xb, xsq, nullptr, 0);
    prep_rows<<<384, 256, 0, stream>>>(wqkv, wqb, wqsq, nullptr, 0);
    prep_rows<<<128, 256, 0, stream>>>(wout, wob, wosq, wors, 1);

    gemm_cdist<0><<<dim3(64, 12), 256, 0, stream>>>(xb, wqb, xsq, wqsq, nullptr,
                                                    qkv, nullptr, ksqc, 1536, 512);
    flash_attn<<<dim3(32, 32), 128, 0, stream>>>(qkv, qkv + HSZ, qkv + 2 * HSZ, ksqc, outp);
    outsq_kernel<<<2048, 256, 0, stream>>>(outp, osq);
    gemm_cdist<1><<<dim3(64, 4), 256, 0, stream>>>(outp, wob, osq, wosq, wors,
                                                   nullptr, out, nullptr, 512, 512);
}

// Round 3
// 202.679 us; speedup vs baseline: 1.2912x; 1.0382x over previous
//
#include <hip/hip_runtime.h>
#include <stdint.h>

typedef float v4f __attribute__((ext_vector_type(4)));
typedef short v8s __attribute__((ext_vector_type(8)));
typedef uint32_t u32;

#define DEVI static __device__ __forceinline__

// fp32 -> bf16 (RNE), raw bits
DEVI unsigned short f2bf(float f) {
    u32 u = __builtin_bit_cast(u32, f);
    u = (u + 0x7fffu + ((u >> 16) & 1u)) >> 16;
    return (unsigned short)u;
}
DEVI float bf2f(unsigned short h) {
    u32 u = ((u32)h) << 16;
    return __builtin_bit_cast(float, u);
}

// async global->LDS, 16B per lane. HW dest = wave-uniform base + lane*16,
// which matches all call sites below (lds ptr is linear in lane).
template <typename T>
DEVI void async16(const T* g, T* l) {
    __builtin_amdgcn_global_load_lds(
        (const __attribute__((address_space(1))) u32*)g,
        (__attribute__((address_space(3))) u32*)l, 16, 0, 0);
}

DEVI v4f bmfma(v8s a, v8s b, v4f c) {
    return __builtin_amdgcn_mfma_f32_16x16x32_bf16(a, b, c, 0, 0, 0);
}

static const size_t HSZ = 32ull * 2048 * 64;  // per q/k/v region, elements

// ---------------------------------------------------------------------------
// prep: fp32 [R][512] -> bf16, row sum-of-squares, optional row sum.
__launch_bounds__(256, 2)
__global__ void prep_rows(const float* __restrict__ X, unsigned short* __restrict__ Xb,
                          float* __restrict__ Sq, float* __restrict__ Rs, int hasRs)
{
    const int w = threadIdx.x >> 6, lane = threadIdx.x & 63;
    const int r = blockIdx.x * 4 + w;
    const float* xr = X + (size_t)r * 512 + lane * 8;
    float4 a = *(const float4*)xr;
    float4 c = *(const float4*)(xr + 4);
    float s = a.x*a.x + a.y*a.y + a.z*a.z + a.w*a.w
            + c.x*c.x + c.y*c.y + c.z*c.z + c.w*c.w;
    float sm = a.x + a.y + a.z + a.w + c.x + c.y + c.z + c.w;
    uint4 pkv;
    unsigned short* e = (unsigned short*)&pkv;
    e[0] = f2bf(a.x); e[1] = f2bf(a.y); e[2] = f2bf(a.z); e[3] = f2bf(a.w);
    e[4] = f2bf(c.x); e[5] = f2bf(c.y); e[6] = f2bf(c.z); e[7] = f2bf(c.w);
    *(uint4*)(Xb + (size_t)r * 512 + lane * 8) = pkv;
#pragma unroll
    for (int d = 32; d > 0; d >>= 1) {
        s  += __shfl_xor(s, d);
        sm += __shfl_xor(sm, d);
    }
    if (lane == 0) { Sq[r] = s; if (hasRs) Rs[r] = sm; }
}

// ---------------------------------------------------------------------------
// out_sq = sum_d (out'[r][d] + 32)^2 over bf16 out' [8192][512]; wave per row.
__launch_bounds__(256, 2)
__global__ void outsq_kernel(const unsigned short* __restrict__ Op, float* __restrict__ Osq)
{
    const int w = threadIdx.x >> 6, lane = threadIdx.x & 63;
    const int r = blockIdx.x * 4 + w;
    uint4 pk = *(const uint4*)(Op + (size_t)r * 512 + lane * 8);
    const unsigned short* e = (const unsigned short*)&pk;
    float s = 0.f;
#pragma unroll
    for (int u = 0; u < 8; ++u) { float f = bf2f(e[u]) + 32.f; s += f * f; }
#pragma unroll
    for (int d = 32; d > 0; d >>= 1) s += __shfl_xor(s, d);
    if (lane == 0) Osq[r] = s;
}

// ---------------------------------------------------------------------------
// QKV cdist GEMM. 128x128 tile, BK=64, 4 waves, 16x16x32 bf16 MFMA, XOR-8
// swizzle, global_load_lds width-16 staging. val = sqrt(max(Asq+Bsq-2dot,0))-32.
//   tt=0 (q): *2*scale*log2e -> q'' region [bh][i][d]
//   tt=1 (k): -> k' region [bh][j][d]; fused ksqc[bh][j] = sum_d k'^2 * CK
//   tt=2 (v): -> v' region TRANSPOSED [bh][d][j]
__launch_bounds__(256, 2)
__global__ void gemm_cdist(const unsigned short* __restrict__ A,
                           const unsigned short* __restrict__ B,
                           const float* __restrict__ Asq,
                           const float* __restrict__ Bsq,
                           unsigned short* __restrict__ QKV,
                           float* __restrict__ Ksqc)
{
    __shared__ unsigned short lA[128 * 64];
    __shared__ unsigned short lB[128 * 64];
    const int t = threadIdx.x;
    const int lane = t & 63, w = t >> 6;
    const int low = lane & 15, quad = lane >> 4;
    const int wm = w & 1, wn = w >> 1;
    const int tM = blockIdx.x * 128, tN = blockIdx.y * 128;

    v4f acc[4][4];
#pragma unroll
    for (int a = 0; a < 4; ++a)
#pragma unroll
        for (int b = 0; b < 4; ++b) acc[a][b] = (v4f){0.f, 0.f, 0.f, 0.f};

    for (int kt = 0; kt < 512; kt += 64) {
        __syncthreads();
#pragma unroll
        for (int is = 0; is < 4; ++is) {
            int slot = is * 256 + t;
            int r = slot >> 3, bp = slot & 7;
            int bs = bp ^ (r & 7);
            async16(A + (size_t)(tM + r) * 512 + kt + bs * 8, lA + slot * 8);
            async16(B + (size_t)(tN + r) * 512 + kt + bs * 8, lB + slot * 8);
        }
        __syncthreads();

        v8s bfr[4][2];
#pragma unroll
        for (int ns = 0; ns < 4; ++ns) {
            int row = wn * 64 + ns * 16 + low;
#pragma unroll
            for (int kc = 0; kc < 2; ++kc)
                bfr[ns][kc] = *(const v8s*)(lB + (row * 8 + ((kc * 4 + quad) ^ (row & 7))) * 8);
        }
#pragma unroll
        for (int ms = 0; ms < 4; ++ms) {
            int row = wm * 64 + ms * 16 + low;
            v8s af0 = *(const v8s*)(lA + (row * 8 + ((0 + quad) ^ (row & 7))) * 8);
            v8s af1 = *(const v8s*)(lA + (row * 8 + ((4 + quad) ^ (row & 7))) * 8);
#pragma unroll
            for (int ns = 0; ns < 4; ++ns) {
                acc[ms][ns] = bmfma(af0, bfr[ns][0], acc[ms][ns]);
                acc[ms][ns] = bmfma(af1, bfr[ns][1], acc[ms][ns]);
            }
        }
    }

    const int tt = tN >> 9;  // block-uniform region id
#pragma unroll
    for (int ms = 0; ms < 4; ++ms) {
#pragma unroll
        for (int reg = 0; reg < 4; ++reg) {
            const int row = tM + wm * 64 + ms * 16 + quad * 4 + reg;
            const int b = row >> 11, i = row & 2047;
            float kacc = 0.f;
#pragma unroll
            for (int ns = 0; ns < 4; ++ns) {
                const int col = tN + wn * 64 + ns * 16 + low;
                float dot = acc[ms][ns][reg];
                float val = sqrtf(fmaxf(Asq[row] + Bsq[col] - 2.f * dot, 0.f)) - 32.f;
                int h = (col >> 6) & 7, d = col & 63, bh = b * 8 + h;
                if (tt == 0) {
                    QKV[((size_t)bh * 2048 + i) * 64 + d] =
                        f2bf(val * 0.36067376022224085f);  // 2*scale*log2e
                } else if (tt == 1) {
                    QKV[HSZ + ((size_t)bh * 2048 + i) * 64 + d] = f2bf(val);
                    kacc += val * val;
                } else {
                    QKV[2 * HSZ + ((size_t)(bh * 64 + d)) * 2048 + i] = f2bf(val);
                }
            }
            if (tt == 1) {
#pragma unroll
                for (int d = 1; d < 16; d <<= 1) kacc += __shfl_xor(kacc, d);
                if (low == 0) {
                    int h = ((tN + wn * 64) >> 6) & 7;
                    Ksqc[(size_t)(b * 8 + h) * 2048 + i] = kacc * 0.18033688011112042f;
                }
            }
        }
    }
}

// ---------------------------------------------------------------------------
// Flash attention, static-bound softmax, KV-split=2.
// Block: 2 waves x 32 Q-rows = 64 rows; handles j in [sp*1024, sp*1024+1024).
// Writes unnormalized partial O (bf16) and partial l (f32); combine normalizes.
__launch_bounds__(128, 3)
__global__ void flash_attn(const unsigned short* __restrict__ Q,
                           const unsigned short* __restrict__ K,
                           const unsigned short* __restrict__ VT,
                           const float* __restrict__ Ksqc,
                           unsigned short* __restrict__ PO,
                           float* __restrict__ PL)
{
    __shared__ unsigned short lK[64 * 64];        // [j][d], XOR-8 swizzle
    __shared__ unsigned short lV[64 * 64];        // [d][j], XOR-8 swizzle
    __shared__ float lKq[64];
    __shared__ __align__(16) u32 lP2[2][16 * 68]; // per wave: 16 row-pairs x 64 j (+pad)

    const int t = threadIdx.x, lane = t & 63, w = t >> 6;
    const int low = lane & 15, quad = lane >> 4;
    const int qt = blockIdx.x, bh = blockIdx.y, sp = blockIdx.z;
    const size_t base = (size_t)bh * (2048 * 64);
    const int row0 = qt * 64 + w * 32;
    const int j0 = sp * 1024;

    // Q fragments: rows row0 + g*16 + low
    v8s qf[2][2];
#pragma unroll
    for (int g = 0; g < 2; ++g)
#pragma unroll
        for (int kc = 0; kc < 2; ++kc)
            qf[g][kc] = *(const v8s*)(Q + base + (size_t)(row0 + g * 16 + low) * 64
                                      + kc * 32 + quad * 8);

    // static per-row softmax shift (pre-scaled exp2 domain)
    v4f negmq[2];
#pragma unroll
    for (int g = 0; g < 2; ++g) {
        float s = 0.f;
#pragma unroll
        for (int kc = 0; kc < 2; ++kc) {
            const unsigned short* qe = (const unsigned short*)&qf[g][kc];
#pragma unroll
            for (int u = 0; u < 8; ++u) { float f = bf2f(qe[u]); s += f * f; }
        }
        s += __shfl_xor(s, 16);
        s += __shfl_xor(s, 32);
        float m = s * 1.3862943611198906f;
#pragma unroll
        for (int r = 0; r < 4; ++r) negmq[g][r] = -__shfl(m, quad * 4 + r);
    }

    const v8s ONES = (v8s){0x3F80, 0x3F80, 0x3F80, 0x3F80,
                           0x3F80, 0x3F80, 0x3F80, 0x3F80};  // bf16 1.0

    v4f o[2][4], lacc[2];
#pragma unroll
    for (int g = 0; g < 2; ++g) {
        lacc[g] = (v4f){0.f, 0.f, 0.f, 0.f};
#pragma unroll
        for (int ds = 0; ds < 4; ++ds) o[g][ds] = (v4f){0.f, 0.f, 0.f, 0.f};
    }

    // hoisted loop-carried global pointers
    const unsigned short* kg = K + base + (size_t)j0 * 64;
    const unsigned short* vg = VT + (size_t)bh * 64 * 2048 + j0;
    const float* kqg = Ksqc + (size_t)bh * 2048 + j0;

    for (int it = 0; it < 16; ++it) {
        __syncthreads();
#pragma unroll
        for (int is = 0; is < 4; ++is) {
            int slot = is * 128 + t;
            int r = slot >> 3, bp = slot & 7, bs = bp ^ (r & 7);
            async16(kg + (size_t)r * 64 + bs * 8, lK + slot * 8);
        }
#pragma unroll
        for (int is = 0; is < 4; ++is) {
            int slot = is * 128 + t;
            int r = slot >> 3, bp = slot & 7, bs = bp ^ (r & 7);
            async16(vg + (size_t)r * 2048 + bs * 8, lV + slot * 8);
        }
        if (t < 16) async16(kqg + t * 4, lKq + t * 4);
        __syncthreads();
        kg += 64 * 64; vg += 64; kqg += 64;

        // ---- S phase ----
#pragma unroll
        for (int js = 0; js < 4; ++js) {
            const int krow = js * 16 + low;
            v8s kf0 = *(const v8s*)(lK + (krow * 8 + ((0 + quad) ^ (krow & 7))) * 8);
            v8s kf1 = *(const v8s*)(lK + (krow * 8 + ((4 + quad) ^ (krow & 7))) * 8);
            float kq = lKq[krow];
#pragma unroll
            for (int g = 0; g < 2; ++g) {
                v4f sa = negmq[g];
                sa = bmfma(qf[g][0], kf0, sa);
                sa = bmfma(qf[g][1], kf1, sa);
                float pv0 = exp2f(sa[0] - kq);
                float pv1 = exp2f(sa[1] - kq);
                float pv2 = exp2f(sa[2] - kq);
                float pv3 = exp2f(sa[3] - kq);
                // truncating bf16 pack (bias cancels in softmax ratio)
                u32 pk0 = __builtin_amdgcn_perm(__builtin_bit_cast(u32, pv1),
                                                __builtin_bit_cast(u32, pv0),
                                                0x07060302u);
                u32 pk1 = __builtin_amdgcn_perm(__builtin_bit_cast(u32, pv3),
                                                __builtin_bit_cast(u32, pv2),
                                                0x07060302u);
                lP2[w][(g * 8 + quad * 2 + 0) * 68 + krow] = pk0;
                lP2[w][(g * 8 + quad * 2 + 1) * 68 + krow] = pk1;
            }
        }

        // wave-local P2 write->read ordering
        __asm__ volatile("s_waitcnt lgkmcnt(0)" ::: "memory");

        // ---- unpack P fragments ----
        v8s pf[2][2];
#pragma unroll
        for (int g = 0; g < 2; ++g)
#pragma unroll
            for (int kc = 0; kc < 2; ++kc) {
                const u32* pb = &lP2[w][(g * 8 + (low >> 1)) * 68 + kc * 32 + quad * 8];
                uint4 q0 = *(const uint4*)pb;
                uint4 q1 = *(const uint4*)(pb + 4);
                u32 sel = (low & 1) ? 0x07060302u : 0x05040100u;
                uint4 dd;
                dd.x = __builtin_amdgcn_perm(q0.y, q0.x, sel);
                dd.y = __builtin_amdgcn_perm(q0.w, q0.z, sel);
                dd.z = __builtin_amdgcn_perm(q1.y, q1.x, sel);
                dd.w = __builtin_amdgcn_perm(q1.w, q1.z, sel);
                pf[g][kc] = __builtin_bit_cast(v8s, dd);
            }

        // ---- l via ones-MFMA (matrix pipe, replaces 32 VALU adds) ----
        lacc[0] = bmfma(pf[0][0], ONES, lacc[0]);
        lacc[0] = bmfma(pf[0][1], ONES, lacc[0]);
        lacc[1] = bmfma(pf[1][0], ONES, lacc[1]);
        lacc[1] = bmfma(pf[1][1], ONES, lacc[1]);

        // ---- PV phase ----
#pragma unroll
        for (int ds = 0; ds < 4; ++ds) {
            const int dd2 = ds * 16 + low;
#pragma unroll
            for (int kc = 0; kc < 2; ++kc) {
                v8s vf = *(const v8s*)(lV + (dd2 * 8 + ((kc * 4 + quad) ^ (dd2 & 7))) * 8);
                o[0][ds] = bmfma(pf[0][kc], vf, o[0][ds]);
                o[1][ds] = bmfma(pf[1][kc], vf, o[1][ds]);
            }
        }
    }

    // epilogue: store partials (unnormalized)
    const int pb = (qt * 32 + bh) * 2 + sp;
    unsigned short* pob = PO + (size_t)pb * 4096;
#pragma unroll
    for (int g = 0; g < 2; ++g) {
#pragma unroll
        for (int ds = 0; ds < 4; ++ds)
#pragma unroll
            for (int r = 0; r < 4; ++r) {
                int rl = w * 32 + g * 16 + quad * 4 + r;
                pob[rl * 64 + ds * 16 + low] = f2bf(o[g][ds][r]);
            }
        if (low == 0) {
#pragma unroll
            for (int r = 0; r < 4; ++r)
                PL[(size_t)pb * 64 + w * 32 + g * 16 + quad * 4 + r] = lacc[g][r];
        }
    }
}

// ---------------------------------------------------------------------------
// combine: outp[i][h*64+d] = (po0+po1)/(l0+l1), bf16. Grid (32 qt, 32 bh) x 256.
__launch_bounds__(256, 2)
__global__ void combine_kernel(const unsigned short* __restrict__ PO,
                               const float* __restrict__ PL,
                               unsigned short* __restrict__ O)
{
    const int qt = blockIdx.x, bh = blockIdx.y, t = threadIdx.x;
    const int b = bh >> 3, h = bh & 7;
    const int pbase = (qt * 32 + bh) * 2;
    const int row = t >> 2, c0 = (t & 3) * 16;
    float inv = 1.f / (PL[(size_t)pbase * 64 + row] + PL[(size_t)(pbase + 1) * 64 + row]);
    const unsigned short* a = PO + (size_t)pbase * 4096 + row * 64 + c0;
    const unsigned short* bb = a + 4096;
    uint4 a0 = *(const uint4*)a,  a1 = *(const uint4*)(a + 8);
    uint4 b0 = *(const uint4*)bb, b1 = *(const uint4*)(bb + 8);
    const unsigned short* ae = (const unsigned short*)&a0;
    const unsigned short* be = (const unsigned short*)&b0;
    uint4 o0, o1;
    unsigned short* oe = (unsigned short*)&o0;
#pragma unroll
    for (int u = 0; u < 8; ++u) oe[u] = f2bf((bf2f(ae[u]) + bf2f(be[u])) * inv);
    ae = (const unsigned short*)&a1; be = (const unsigned short*)&b1;
    oe = (unsigned short*)&o1;
#pragma unroll
    for (int u = 0; u < 8; ++u) oe[u] = f2bf((bf2f(ae[u]) + bf2f(be[u])) * inv);
    unsigned short* dst = O + ((size_t)(b * 2048 + qt * 64 + row)) * 512 + h * 64 + c0;
    *(uint4*)dst = o0;
    *(uint4*)(dst + 8) = o1;
}

// ---------------------------------------------------------------------------
// Output cdist GEMM: 128x64 tiles -> grid (64,8)=512 blocks (2/CU).
// val = sqrt(max(Asq+Bsq-2(dot+32*Brs),0)) -> fp32 OUT [8192][512].
__launch_bounds__(256, 2)
__global__ void gemm_out(const unsigned short* __restrict__ A,
                         const unsigned short* __restrict__ B,
                         const float* __restrict__ Asq,
                         const float* __restrict__ Bsq,
                         const float* __restrict__ Brs,
                         float* __restrict__ OUT)
{
    __shared__ unsigned short lA[128 * 64];
    __shared__ unsigned short lB[64 * 64];
    const int t = threadIdx.x;
    const int lane = t & 63, w = t >> 6;
    const int low = lane & 15, quad = lane >> 4;
    const int wm = w & 1, wn = w >> 1;
    const int tM = blockIdx.x * 128, tN = blockIdx.y * 64;

    v4f acc[4][2];
#pragma unroll
    for (int a = 0; a < 4; ++a)
#pragma unroll
        for (int b = 0; b < 2; ++b) acc[a][b] = (v4f){0.f, 0.f, 0.f, 0.f};

    for (int kt = 0; kt < 512; kt += 64) {
        __syncthreads();
#pragma unroll
        for (int is = 0; is < 4; ++is) {
            int slot = is * 256 + t;
            int r = slot >> 3, bp = slot & 7, bs = bp ^ (r & 7);
            async16(A + (size_t)(tM + r) * 512 + kt + bs * 8, lA + slot * 8);
        }
#pragma unroll
        for (int is = 0; is < 2; ++is) {
            int slot = is * 256 + t;
            int r = slot >> 3, bp = slot & 7, bs = bp ^ (r & 7);
            async16(B + (size_t)(tN + r) * 512 + kt + bs * 8, lB + slot * 8);
        }
        __syncthreads();

        v8s bfr[2][2];
#pragma unroll
        for (int ns = 0; ns < 2; ++ns) {
            int row = wn * 32 + ns * 16 + low;
#pragma unroll
            for (int kc = 0; kc < 2; ++kc)
                bfr[ns][kc] = *(const v8s*)(lB + (row * 8 + ((kc * 4 + quad) ^ (row & 7))) * 8);
        }
#pragma unroll
        for (int ms = 0; ms < 4; ++ms) {
            int row = wm * 64 + ms * 16 + low;
            v8s af0 = *(const v8s*)(lA + (row * 8 + ((0 + quad) ^ (row & 7))) * 8);
            v8s af1 = *(const v8s*)(lA + (row * 8 + ((4 + quad) ^ (row & 7))) * 8);
#pragma unroll
            for (int ns = 0; ns < 2; ++ns) {
                acc[ms][ns] = bmfma(af0, bfr[ns][0], acc[ms][ns]);
                acc[ms][ns] = bmfma(af1, bfr[ns][1], acc[ms][ns]);
            }
        }
    }

#pragma unroll
    for (int ms = 0; ms < 4; ++ms) {
#pragma unroll
        for (int ns = 0; ns < 2; ++ns) {
#pragma unroll
            for (int reg = 0; reg < 4; ++reg) {
                int row = tM + wm * 64 + ms * 16 + quad * 4 + reg;
                int col = tN + wn * 32 + ns * 16 + low;
                float val = sqrtf(fmaxf(Asq[row] + Bsq[col]
                                        - 2.f * (acc[ms][ns][reg] + 32.f * Brs[col]), 0.f));
                OUT[(size_t)row * 512 + col] = val;
            }
        }
    }
}

// ---------------------------------------------------------------------------
extern "C" void kernel_launch(void* const* d_in, const int* in_sizes, int n_in,
                              void* d_out, int out_size, void* d_ws, size_t ws_size,
                              hipStream_t stream)
{
    const float* x    = (const float*)d_in[0];   // [4,2048,512]
    const float* wqkv = (const float*)d_in[1];   // [1536,512]
    const float* wout = (const float*)d_in[2];   // [512,512]
    float* out = (float*)d_out;                  // [4,2048,512] fp32

    char* ws = (char*)d_ws;
    size_t off = 0;
    auto alloc = [&](size_t bytes) -> void* {
        void* p = ws + off;
        off += (bytes + 255) & ~(size_t)255;
        return p;
    };
    unsigned short* xb   = (unsigned short*)alloc(8192ull * 512 * 2);
    unsigned short* wqb  = (unsigned short*)alloc(1536ull * 512 * 2);
    unsigned short* wob  = (unsigned short*)alloc(512ull * 512 * 2);
    unsigned short* qkv  = (unsigned short*)alloc(3ull * HSZ * 2);  // q'', k', v'^T
    unsigned short* outp = (unsigned short*)alloc(8192ull * 512 * 2);
    unsigned short* po   = (unsigned short*)alloc(2048ull * 4096 * 2);  // partial O
    float* pl   = (float*)alloc(2048ull * 64 * 4);                      // partial l
    float* xsq  = (float*)alloc(8192 * 4);
    float* wqsq = (float*)alloc(1536 * 4);
    float* wosq = (float*)alloc(512 * 4);
    float* wors = (float*)alloc(512 * 4);
    float* ksqc = (float*)alloc(65536ull * 4);
    float* osq  = (float*)alloc(8192 * 4);

    prep_rows<<<2048, 256, 0, stream>>>(x, xb, xsq, nullptr, 0);
    prep_rows<<<384, 256, 0, stream>>>(wqkv, wqb, wqsq, nullptr, 0);
    prep_rows<<<128, 256, 0, stream>>>(wout, wob, wosq, wors, 1);

    gemm_cdist<<<dim3(64, 12), 256, 0, stream>>>(xb, wqb, xsq, wqsq, qkv, ksqc);
    flash_attn<<<dim3(32, 32, 2), 128, 0, stream>>>(qkv, qkv + HSZ, qkv + 2 * HSZ,
                                                    ksqc, po, pl);
    combine_kernel<<<dim3(32, 32), 256, 0, stream>>>(po, pl, outp);
    outsq_kernel<<<2048, 256, 0, stream>>>(outp, osq);
    gemm_out<<<dim3(64, 8), 256, 0, stream>>>(outp, wob, osq, wosq, wors, out);
}

// Round 4
// 185.646 us; speedup vs baseline: 1.4096x; 1.0918x over previous
//
#include <hip/hip_runtime.h>
#include <stdint.h>

typedef float v4f  __attribute__((ext_vector_type(4)));
typedef float v16f __attribute__((ext_vector_type(16)));
typedef short v8s  __attribute__((ext_vector_type(8)));
typedef uint32_t u32;

#define DEVI static __device__ __forceinline__

// fp32 -> bf16 (RNE), raw bits
DEVI unsigned short f2bf(float f) {
    u32 u = __builtin_bit_cast(u32, f);
    u = (u + 0x7fffu + ((u >> 16) & 1u)) >> 16;
    return (unsigned short)u;
}
DEVI float bf2f(unsigned short h) {
    u32 u = ((u32)h) << 16;
    return __builtin_bit_cast(float, u);
}

// async global->LDS, 16B per lane. HW dest = wave-uniform base + lane*16.
template <typename T>
DEVI void async16(const T* g, T* l) {
    __builtin_amdgcn_global_load_lds(
        (const __attribute__((address_space(1))) u32*)g,
        (__attribute__((address_space(3))) u32*)l, 16, 0, 0);
}

DEVI v4f bmfma(v8s a, v8s b, v4f c) {
    return __builtin_amdgcn_mfma_f32_16x16x32_bf16(a, b, c, 0, 0, 0);
}
DEVI v16f bmfma32(v8s a, v8s b, v16f c) {
    return __builtin_amdgcn_mfma_f32_32x32x16_bf16(a, b, c, 0, 0, 0);
}

static const size_t HSZ = 32ull * 2048 * 64;  // per q/k/v region, elements

// ---------------------------------------------------------------------------
// prep: fp32 [R][512] -> bf16, row sum-of-squares, optional row sum.
__launch_bounds__(256, 2)
__global__ void prep_rows(const float* __restrict__ X, unsigned short* __restrict__ Xb,
                          float* __restrict__ Sq, float* __restrict__ Rs, int hasRs)
{
    const int w = threadIdx.x >> 6, lane = threadIdx.x & 63;
    const int r = blockIdx.x * 4 + w;
    const float* xr = X + (size_t)r * 512 + lane * 8;
    float4 a = *(const float4*)xr;
    float4 c = *(const float4*)(xr + 4);
    float s = a.x*a.x + a.y*a.y + a.z*a.z + a.w*a.w
            + c.x*c.x + c.y*c.y + c.z*c.z + c.w*c.w;
    float sm = a.x + a.y + a.z + a.w + c.x + c.y + c.z + c.w;
    uint4 pkv;
    unsigned short* e = (unsigned short*)&pkv;
    e[0] = f2bf(a.x); e[1] = f2bf(a.y); e[2] = f2bf(a.z); e[3] = f2bf(a.w);
    e[4] = f2bf(c.x); e[5] = f2bf(c.y); e[6] = f2bf(c.z); e[7] = f2bf(c.w);
    *(uint4*)(Xb + (size_t)r * 512 + lane * 8) = pkv;
#pragma unroll
    for (int d = 32; d > 0; d >>= 1) {
        s  += __shfl_xor(s, d);
        sm += __shfl_xor(sm, d);
    }
    if (lane == 0) { Sq[r] = s; if (hasRs) Rs[r] = sm; }
}

// ---------------------------------------------------------------------------
// out_sq = sum_d (out'[r][d] + 32)^2 over bf16 out' [8192][512]; wave per row.
__launch_bounds__(256, 2)
__global__ void outsq_kernel(const unsigned short* __restrict__ Op, float* __restrict__ Osq)
{
    const int w = threadIdx.x >> 6, lane = threadIdx.x & 63;
    const int r = blockIdx.x * 4 + w;
    uint4 pk = *(const uint4*)(Op + (size_t)r * 512 + lane * 8);
    const unsigned short* e = (const unsigned short*)&pk;
    float s = 0.f;
#pragma unroll
    for (int u = 0; u < 8; ++u) { float f = bf2f(e[u]) + 32.f; s += f * f; }
#pragma unroll
    for (int d = 32; d > 0; d >>= 1) s += __shfl_xor(s, d);
    if (lane == 0) Osq[r] = s;
}

// ---------------------------------------------------------------------------
// QKV cdist GEMM. 128x128 tile, BK=64, 4 waves, 16x16x32 bf16 MFMA, XOR-8
// swizzle, global_load_lds width-16 staging. val = sqrt(max(Asq+Bsq-2dot,0))-32.
//   tt=0 (q): *2*scale*log2e -> q'' region [bh][i][d]
//   tt=1 (k): -> k' region [bh][j][d]; fused ksqc[bh][j] = sum_d k'^2 * CK
//   tt=2 (v): -> v' region TRANSPOSED [bh][d][j], via LDS-transpose epilogue
__launch_bounds__(256, 2)
__global__ void gemm_cdist(const unsigned short* __restrict__ A,
                           const unsigned short* __restrict__ B,
                           const float* __restrict__ Asq,
                           const float* __restrict__ Bsq,
                           unsigned short* __restrict__ QKV,
                           float* __restrict__ Ksqc)
{
    __shared__ unsigned short lsm[2 * 128 * 64];   // lA | lB; reused as lT in epilogue
    unsigned short* lA = lsm;
    unsigned short* lB = lsm + 128 * 64;
    const int t = threadIdx.x;
    const int lane = t & 63, w = t >> 6;
    const int low = lane & 15, quad = lane >> 4;
    const int wm = w & 1, wn = w >> 1;
    const int tM = blockIdx.x * 128, tN = blockIdx.y * 128;

    v4f acc[4][4];
#pragma unroll
    for (int a = 0; a < 4; ++a)
#pragma unroll
        for (int b = 0; b < 4; ++b) acc[a][b] = (v4f){0.f, 0.f, 0.f, 0.f};

    for (int kt = 0; kt < 512; kt += 64) {
        __syncthreads();
#pragma unroll
        for (int is = 0; is < 4; ++is) {
            int slot = is * 256 + t;
            int r = slot >> 3, bp = slot & 7;
            int bs = bp ^ (r & 7);
            async16(A + (size_t)(tM + r) * 512 + kt + bs * 8, lA + slot * 8);
            async16(B + (size_t)(tN + r) * 512 + kt + bs * 8, lB + slot * 8);
        }
        __syncthreads();

        v8s bfr[4][2];
#pragma unroll
        for (int ns = 0; ns < 4; ++ns) {
            int row = wn * 64 + ns * 16 + low;
#pragma unroll
            for (int kc = 0; kc < 2; ++kc)
                bfr[ns][kc] = *(const v8s*)(lB + (row * 8 + ((kc * 4 + quad) ^ (row & 7))) * 8);
        }
#pragma unroll
        for (int ms = 0; ms < 4; ++ms) {
            int row = wm * 64 + ms * 16 + low;
            v8s af0 = *(const v8s*)(lA + (row * 8 + ((0 + quad) ^ (row & 7))) * 8);
            v8s af1 = *(const v8s*)(lA + (row * 8 + ((4 + quad) ^ (row & 7))) * 8);
#pragma unroll
            for (int ns = 0; ns < 4; ++ns) {
                acc[ms][ns] = bmfma(af0, bfr[ns][0], acc[ms][ns]);
                acc[ms][ns] = bmfma(af1, bfr[ns][1], acc[ms][ns]);
            }
        }
    }

    const int tt = tN >> 9;  // block-uniform region id
    if (tt != 2) {
#pragma unroll
        for (int ms = 0; ms < 4; ++ms) {
#pragma unroll
            for (int reg = 0; reg < 4; ++reg) {
                const int row = tM + wm * 64 + ms * 16 + quad * 4 + reg;
                const int b = row >> 11, i = row & 2047;
                float kacc = 0.f;
#pragma unroll
                for (int ns = 0; ns < 4; ++ns) {
                    const int col = tN + wn * 64 + ns * 16 + low;
                    float dot = acc[ms][ns][reg];
                    float val = sqrtf(fmaxf(Asq[row] + Bsq[col] - 2.f * dot, 0.f)) - 32.f;
                    int h = (col >> 6) & 7, d = col & 63, bh = b * 8 + h;
                    if (tt == 0) {
                        QKV[((size_t)bh * 2048 + i) * 64 + d] =
                            f2bf(val * 0.36067376022224085f);  // 2*scale*log2e
                    } else {
                        QKV[HSZ + ((size_t)bh * 2048 + i) * 64 + d] = f2bf(val);
                        kacc += val * val;
                    }
                }
                if (tt == 1) {
#pragma unroll
                    for (int d = 1; d < 16; d <<= 1) kacc += __shfl_xor(kacc, d);
                    if (low == 0) {
                        int h = ((tN + wn * 64) >> 6) & 7;
                        Ksqc[(size_t)(b * 8 + h) * 2048 + i] = kacc * 0.18033688011112042f;
                    }
                }
            }
        }
    } else {
        // v blocks: compute all vals, then 2-pass LDS transpose for coalesced
        // [bh][d][i] stores. lT: [col 0..127][row 0..63], stride 72 shorts.
        u32 packed[4][4][2];
#pragma unroll
        for (int ms = 0; ms < 4; ++ms)
#pragma unroll
            for (int ns = 0; ns < 4; ++ns) {
                const int col = tN + wn * 64 + ns * 16 + low;
                float bs_ = Bsq[col];
#pragma unroll
                for (int rp = 0; rp < 2; ++rp) {
                    u32 pk = 0;
#pragma unroll
                    for (int sub = 0; sub < 2; ++sub) {
                        int reg = rp * 2 + sub;
                        int row = tM + wm * 64 + ms * 16 + quad * 4 + reg;
                        float val = sqrtf(fmaxf(Asq[row] + bs_
                                                - 2.f * acc[ms][ns][reg], 0.f)) - 32.f;
                        pk |= (u32)f2bf(val) << (16 * sub);
                    }
                    packed[ms][ns][rp] = pk;
                }
            }
        u32* lT32 = (u32*)lsm;
        const int colL = wn * 64 + (t & 15) + ((lane >> 4) & 0) /*keep expr simple*/;
#pragma unroll
        for (int p = 0; p < 2; ++p) {
            __syncthreads();
            if (wm == p) {
#pragma unroll
                for (int ms = 0; ms < 4; ++ms)
#pragma unroll
                    for (int ns = 0; ns < 4; ++ns) {
                        int cl = wn * 64 + ns * 16 + low;
#pragma unroll
                        for (int rp = 0; rp < 2; ++rp)
                            lT32[cl * 36 + ms * 8 + quad * 2 + rp] = packed[ms][ns][rp];
                    }
            }
            __syncthreads();
#pragma unroll
            for (int cc = 0; cc < 4; ++cc) {
                int col = cc * 32 + (t >> 3);
                int i0 = (t & 7) * 8;
                uint4 vvv = *(const uint4*)(lsm + col * 72 + i0);
                int colg = tN + col;
                int h = (colg >> 6) & 7, d = colg & 63;
                int rowg = tM + p * 64 + i0;
                int b = rowg >> 11, i = rowg & 2047;
                *(uint4*)(QKV + 2 * HSZ
                          + ((size_t)((b * 8 + h) * 64 + d)) * 2048 + i) = vvv;
            }
        }
    }
    (void)0;
}

// ---------------------------------------------------------------------------
// Flash attention v3: 32x32x16 MFMA, S^T = K.Q^T (i lands in lane&31 -> P is
// directly A-operand-shaped up to one xor-32 lane exchange). No P LDS
// round-trip. Block: 2 waves x 64 Q-rows = 128 rows; KV-split=2.
// Writes unnormalized partial O (bf16) + partial l (f32).
__launch_bounds__(128, 2)
__global__ void flash_attn(const unsigned short* __restrict__ Q,
                           const unsigned short* __restrict__ K,
                           const unsigned short* __restrict__ VT,
                           const float* __restrict__ Ksqc,
                           unsigned short* __restrict__ PO,
                           float* __restrict__ PL)
{
    __shared__ unsigned short lK[64 * 64];   // [j][d], XOR-8 swizzle
    __shared__ unsigned short lV[64 * 64];   // [d][j], XOR-8 swizzle
    __shared__ float lKq[64];
    const int t = threadIdx.x, lane = t & 63, w = t >> 6;
    const int i31 = lane & 31, h = lane >> 5;
    const int qt = blockIdx.x, bh = blockIdx.y, sp = blockIdx.z;
    const size_t base = (size_t)bh * (2048 * 64);
    const int row0 = qt * 128 + w * 64;
    const int j0 = sp * 1024;

    // Q fragments (B-operand layout): qfr[it][kt] = Q[row0+32it+i31][16kt+8h..+7]
    v8s qfr[2][4];
#pragma unroll
    for (int it = 0; it < 2; ++it)
#pragma unroll
        for (int kt = 0; kt < 4; ++kt)
            qfr[it][kt] = *(const v8s*)(Q + base
                + (size_t)(row0 + it * 32 + i31) * 64 + kt * 16 + h * 8);

    // static per-row softmax shift: nmq = -q''_sq * 1.3862944 (per-lane scalar)
    float nmq[2];
#pragma unroll
    for (int it = 0; it < 2; ++it) {
        float s = 0.f;
#pragma unroll
        for (int kt = 0; kt < 4; ++kt) {
            const unsigned short* qe = (const unsigned short*)&qfr[it][kt];
#pragma unroll
            for (int u = 0; u < 8; ++u) { float f = bf2f(qe[u]); s += f * f; }
        }
        s += __shfl_xor(s, 32);
        nmq[it] = -s * 1.3862943611198906f;
    }

    v16f o[2][2];
    float lacc[2] = {0.f, 0.f};
#pragma unroll
    for (int it = 0; it < 2; ++it)
#pragma unroll
        for (int dt = 0; dt < 2; ++dt)
#pragma unroll
            for (int r = 0; r < 16; ++r) o[it][dt][r] = 0.f;

    const unsigned short* kg = K + base + (size_t)j0 * 64;
    const unsigned short* vg = VT + (size_t)bh * 64 * 2048 + j0;
    const float* kqg = Ksqc + (size_t)bh * 2048 + j0;

    for (int iter = 0; iter < 16; ++iter) {
        __syncthreads();
#pragma unroll
        for (int is = 0; is < 4; ++is) {
            int slot = is * 128 + t;
            int r = slot >> 3, bp = slot & 7, bs = bp ^ (r & 7);
            async16(kg + (size_t)r * 64 + bs * 8, lK + slot * 8);
        }
#pragma unroll
        for (int is = 0; is < 4; ++is) {
            int slot = is * 128 + t;
            int r = slot >> 3, bp = slot & 7, bs = bp ^ (r & 7);
            async16(vg + (size_t)r * 2048 + bs * 8, lV + slot * 8);
        }
        if (t < 16) async16(kqg + t * 4, lKq + t * 4);
        __syncthreads();
        kg += 64 * 64; vg += 64; kqg += 64;

#pragma unroll
        for (int T = 0; T < 2; ++T) {
            const int jrow = T * 32 + i31;
            v8s kf[4];
#pragma unroll
            for (int kt = 0; kt < 4; ++kt)
                kf[kt] = *(const v8s*)(lK + (jrow * 8 + ((2 * kt + h) ^ (jrow & 7))) * 8);
            v4f kqv[4];
#pragma unroll
            for (int r1 = 0; r1 < 4; ++r1)
                kqv[r1] = *(const v4f*)(lKq + T * 32 + r1 * 8 + h * 4);

            u32 pk[2][8];
#pragma unroll
            for (int it = 0; it < 2; ++it) {
                v16f sa;
#pragma unroll
                for (int r = 0; r < 16; ++r) sa[r] = nmq[it] - kqv[r >> 2][r & 3];
#pragma unroll
                for (int kt = 0; kt < 4; ++kt)
                    sa = bmfma32(kf[kt], qfr[it][kt], sa);
                float p[16];
                float ls = 0.f;
#pragma unroll
                for (int r = 0; r < 16; ++r) { p[r] = exp2f(sa[r]); ls += p[r]; }
                lacc[it] += ls;
#pragma unroll
                for (int r1 = 0; r1 < 4; ++r1) {
                    pk[it][2 * r1] = __builtin_amdgcn_perm(
                        __builtin_bit_cast(u32, p[4 * r1 + 1]),
                        __builtin_bit_cast(u32, p[4 * r1 + 0]), 0x07060302u);
                    pk[it][2 * r1 + 1] = __builtin_amdgcn_perm(
                        __builtin_bit_cast(u32, p[4 * r1 + 3]),
                        __builtin_bit_cast(u32, p[4 * r1 + 2]), 0x07060302u);
                }
            }
            // PV over the two j-16 chunks of this 32-tile
#pragma unroll
            for (int c2 = 0; c2 < 2; ++c2) {
                const int jb = 2 * (2 * T + c2);
                v8s vf[2];
#pragma unroll
                for (int dt = 0; dt < 2; ++dt) {
                    const int drow = dt * 32 + i31;
                    vf[dt] = *(const v8s*)(lV + (drow * 8 + ((jb + h) ^ (drow & 7))) * 8);
                }
#pragma unroll
                for (int it = 0; it < 2; ++it) {
                    u32 pa0 = pk[it][4 * c2 + 0], pa1 = pk[it][4 * c2 + 1];
                    u32 pb0 = pk[it][4 * c2 + 2], pb1 = pk[it][4 * c2 + 3];
                    u32 own0 = h ? pb0 : pa0, own1 = h ? pb1 : pa1;
                    u32 snd0 = h ? pa0 : pb0, snd1 = h ? pa1 : pb1;
                    u32 rcv0 = __shfl_xor(snd0, 32);
                    u32 rcv1 = __shfl_xor(snd1, 32);
                    uint4 dd;
                    dd.x = h ? rcv0 : own0; dd.y = h ? rcv1 : own1;
                    dd.z = h ? own0 : rcv0; dd.w = h ? own1 : rcv1;
                    v8s af = __builtin_bit_cast(v8s, dd);
                    o[it][0] = bmfma32(af, vf[0], o[it][0]);
                    o[it][1] = bmfma32(af, vf[1], o[it][1]);
                }
            }
        }
    }

    // epilogue: store unnormalized partials
    const int pb = (qt * 32 + bh) * 2 + sp;
    unsigned short* pob = PO + (size_t)pb * 8192;
#pragma unroll
    for (int it = 0; it < 2; ++it) lacc[it] += __shfl_xor(lacc[it], 32);
#pragma unroll
    for (int it = 0; it < 2; ++it) {
#pragma unroll
        for (int dt = 0; dt < 2; ++dt)
#pragma unroll
            for (int r = 0; r < 16; ++r) {
                int rl = w * 64 + it * 32 + (r & 3) + 8 * (r >> 2) + 4 * h;
                pob[rl * 64 + dt * 32 + i31] = f2bf(o[it][dt][r]);
            }
        if (h == 0)
            PL[(size_t)pb * 128 + w * 64 + it * 32 + i31] = lacc[it];
    }
}

// ---------------------------------------------------------------------------
// combine: outp[i][h*64+d] = (po0+po1)/(l0+l1), bf16. Grid (32 qt64, 32 bh).
__launch_bounds__(256, 2)
__global__ void combine_kernel(const unsigned short* __restrict__ PO,
                               const float* __restrict__ PL,
                               unsigned short* __restrict__ O)
{
    const int qt = blockIdx.x, bh = blockIdx.y, t = threadIdx.x;
    const int b = bh >> 3, h = bh & 7;
    const int pbase = ((qt >> 1) * 32 + bh) * 2;
    const int rl = (qt & 1) * 64 + (t >> 2), c0 = (t & 3) * 16;
    float inv = 1.f / (PL[(size_t)pbase * 128 + rl] + PL[(size_t)(pbase + 1) * 128 + rl]);
    const unsigned short* a = PO + (size_t)pbase * 8192 + rl * 64 + c0;
    const unsigned short* bb = a + 8192;
    uint4 a0 = *(const uint4*)a,  a1 = *(const uint4*)(a + 8);
    uint4 b0 = *(const uint4*)bb, b1 = *(const uint4*)(bb + 8);
    const unsigned short* ae = (const unsigned short*)&a0;
    const unsigned short* be = (const unsigned short*)&b0;
    uint4 o0, o1;
    unsigned short* oe = (unsigned short*)&o0;
#pragma unroll
    for (int u = 0; u < 8; ++u) oe[u] = f2bf((bf2f(ae[u]) + bf2f(be[u])) * inv);
    ae = (const unsigned short*)&a1; be = (const unsigned short*)&b1;
    oe = (unsigned short*)&o1;
#pragma unroll
    for (int u = 0; u < 8; ++u) oe[u] = f2bf((bf2f(ae[u]) + bf2f(be[u])) * inv);
    unsigned short* dst = O + ((size_t)(b * 2048 + qt * 64 + (t >> 2))) * 512 + h * 64 + c0;
    *(uint4*)dst = o0;
    *(uint4*)(dst + 8) = o1;
}

// ---------------------------------------------------------------------------
// Output cdist GEMM: 128x64 tiles -> grid (64,8)=512 blocks.
// val = sqrt(max(Asq+Bsq-2(dot+32*Brs),0)) -> fp32 OUT [8192][512].
__launch_bounds__(256, 2)
__global__ void gemm_out(const unsigned short* __restrict__ A,
                         const unsigned short* __restrict__ B,
                         const float* __restrict__ Asq,
                         const float* __restrict__ Bsq,
                         const float* __restrict__ Brs,
                         float* __restrict__ OUT)
{
    __shared__ unsigned short lA[128 * 64];
    __shared__ unsigned short lB[64 * 64];
    const int t = threadIdx.x;
    const int lane = t & 63, w = t >> 6;
    const int low = lane & 15, quad = lane >> 4;
    const int wm = w & 1, wn = w >> 1;
    const int tM = blockIdx.x * 128, tN = blockIdx.y * 64;

    v4f acc[4][2];
#pragma unroll
    for (int a = 0; a < 4; ++a)
#pragma unroll
        for (int b = 0; b < 2; ++b) acc[a][b] = (v4f){0.f, 0.f, 0.f, 0.f};

    for (int kt = 0; kt < 512; kt += 64) {
        __syncthreads();
#pragma unroll
        for (int is = 0; is < 4; ++is) {
            int slot = is * 256 + t;
            int r = slot >> 3, bp = slot & 7, bs = bp ^ (r & 7);
            async16(A + (size_t)(tM + r) * 512 + kt + bs * 8, lA + slot * 8);
        }
#pragma unroll
        for (int is = 0; is < 2; ++is) {
            int slot = is * 256 + t;
            int r = slot >> 3, bp = slot & 7, bs = bp ^ (r & 7);
            async16(B + (size_t)(tN + r) * 512 + kt + bs * 8, lB + slot * 8);
        }
        __syncthreads();

        v8s bfr[2][2];
#pragma unroll
        for (int ns = 0; ns < 2; ++ns) {
            int row = wn * 32 + ns * 16 + low;
#pragma unroll
            for (int kc = 0; kc < 2; ++kc)
                bfr[ns][kc] = *(const v8s*)(lB + (row * 8 + ((kc * 4 + quad) ^ (row & 7))) * 8);
        }
#pragma unroll
        for (int ms = 0; ms < 4; ++ms) {
            int row = wm * 64 + ms * 16 + low;
            v8s af0 = *(const v8s*)(lA + (row * 8 + ((0 + quad) ^ (row & 7))) * 8);
            v8s af1 = *(const v8s*)(lA + (row * 8 + ((4 + quad) ^ (row & 7))) * 8);
#pragma unroll
            for (int ns = 0; ns < 2; ++ns) {
                acc[ms][ns] = bmfma(af0, bfr[ns][0], acc[ms][ns]);
                acc[ms][ns] = bmfma(af1, bfr[ns][1], acc[ms][ns]);
            }
        }
    }

#pragma unroll
    for (int ms = 0; ms < 4; ++ms) {
#pragma unroll
        for (int ns = 0; ns < 2; ++ns) {
#pragma unroll
            for (int reg = 0; reg < 4; ++reg) {
                int row = tM + wm * 64 + ms * 16 + quad * 4 + reg;
                int col = tN + wn * 32 + ns * 16 + low;
                float val = sqrtf(fmaxf(Asq[row] + Bsq[col]
                                        - 2.f * (acc[ms][ns][reg] + 32.f * Brs[col]), 0.f));
                OUT[(size_t)row * 512 + col] = val;
            }
        }
    }
}

// ---------------------------------------------------------------------------
extern "C" void kernel_launch(void* const* d_in, const int* in_sizes, int n_in,
                              void* d_out, int out_size, void* d_ws, size_t ws_size,
                              hipStream_t stream)
{
    const float* x    = (const float*)d_in[0];   // [4,2048,512]
    const float* wqkv = (const float*)d_in[1];   // [1536,512]
    const float* wout = (const float*)d_in[2];   // [512,512]
    float* out = (float*)d_out;                  // [4,2048,512] fp32

    char* ws = (char*)d_ws;
    size_t off = 0;
    auto alloc = [&](size_t bytes) -> void* {
        void* p = ws + off;
        off += (bytes + 255) & ~(size_t)255;
        return p;
    };
    unsigned short* xb   = (unsigned short*)alloc(8192ull * 512 * 2);
    unsigned short* wqb  = (unsigned short*)alloc(1536ull * 512 * 2);
    unsigned short* wob  = (unsigned short*)alloc(512ull * 512 * 2);
    unsigned short* qkv  = (unsigned short*)alloc(3ull * HSZ * 2);      // q'', k', v'^T
    unsigned short* outp = (unsigned short*)alloc(8192ull * 512 * 2);
    unsigned short* po   = (unsigned short*)alloc(1024ull * 8192 * 2);  // partial O
    float* pl   = (float*)alloc(1024ull * 128 * 4);                     // partial l
    float* xsq  = (float*)alloc(8192 * 4);
    float* wqsq = (float*)alloc(1536 * 4);
    float* wosq = (float*)alloc(512 * 4);
    float* wors = (float*)alloc(512 * 4);
    float* ksqc = (float*)alloc(65536ull * 4);
    float* osq  = (float*)alloc(8192 * 4);

    prep_rows<<<2048, 256, 0, stream>>>(x, xb, xsq, nullptr, 0);
    prep_rows<<<384, 256, 0, stream>>>(wqkv, wqb, wqsq, nullptr, 0);
    prep_rows<<<128, 256, 0, stream>>>(wout, wob, wosq, wors, 1);

    gemm_cdist<<<dim3(64, 12), 256, 0, stream>>>(xb, wqb, xsq, wqsq, qkv, ksqc);
    flash_attn<<<dim3(16, 32, 2), 128, 0, stream>>>(qkv, qkv + HSZ, qkv + 2 * HSZ,
                                                    ksqc, po, pl);
    combine_kernel<<<dim3(32, 32), 256, 0, stream>>>(po, pl, outp);
    outsq_kernel<<<2048, 256, 0, stream>>>(outp, osq);
    gemm_out<<<dim3(64, 8), 256, 0, stream>>>(outp, wob, osq, wosq, wors, out);
}